// Round 14
// baseline (286.775 us; speedup 1.0000x reference)
//
#include <hip/hip_runtime.h>

#define N_NODES  20000
#define N_EDGES  320000
#define R_REL    40
#define N_BASES  34
#define DIM      128
#define EB       128                         // edges per block (edge GEMM tile M)
#define P_PAD    (N_EDGES + R_REL * EB)      // 325120: worst-case padded relation edges
#define ROOT_PAD ((N_NODES + EB - 1) / EB * EB)  // 20096
#define P2_MAX   (P_PAD + ROOT_PAD)          // 345216 (root edges = slot 40)
#define NE2      (N_EDGES + N_NODES)         // dst-CSR entries incl. root edges
#define NSLOT    (R_REL + 1)                 // 41 weight slots
#define NBLK     (P2_MAX / EB)               // 2697 static edge blocks
#define PADW     (NSLOT * EB)                // 5248 pad-fill threads in place

#define INIT_B   ((N_NODES * R_REL + 255) / 256)   // 3125
#define GATH_B   (N_NODES * 16 / 256)              // 1250
#define WT_B     64                                // 2 layers x 2 rchunks x 4 ktiles x 4 ntiles

typedef unsigned int uint;
typedef unsigned short ushort;
typedef __attribute__((ext_vector_type(8))) short short8;   // 8 bf16 = 4 VGPRs
typedef __attribute__((ext_vector_type(4))) float f32x4;

__device__ __forceinline__ ushort f2bf(float f) {   // RNE fp32 -> bf16
    uint u = __float_as_uint(f);
    return (ushort)((u + 0x7FFFu + ((u >> 16) & 1u)) >> 16);
}
__device__ __forceinline__ uint pk2bf(float a, float b) {
    return (uint)f2bf(a) | ((uint)f2bf(b) << 16);
}

// ---------------- prep: init (zero) + gather-bf16 + wtrans-v2, one dispatch ----------------
// wtrans-v2: block = (layer, rchunk, ktile, ntile); each thread accumulates 20 relations
// per bases element -> bases read once per rchunk (20x less traffic than per-slot loop).
__global__ void prep_kernel(int* __restrict__ c_cnt, int* __restrict__ meta_cur2_deg,
                            const float* __restrict__ emb, const int* __restrict__ idx,
                            ushort* __restrict__ xb,
                            const float* __restrict__ comp0, const float* __restrict__ bases0,
                            const float* __restrict__ root0,
                            const float* __restrict__ comp1, const float* __restrict__ bases1,
                            const float* __restrict__ root1,
                            ushort* __restrict__ Wt) {
    int b = blockIdx.x;
    int t = threadIdx.x;
    if (b < INIT_B) {
        // ---- init ----
        int i = b * 256 + t;
        if (i < N_NODES * R_REL) c_cnt[i] = 0;
        if (i < 256 + 2 * N_NODES) meta_cur2_deg[i] = 0;   // meta[256]+cur2[20000]+deg[20000]
    } else if (b < INIT_B + GATH_B) {
        // ---- gather + bf16 convert ----
        int g = (b - INIT_B) * 256 + t;
        int n = g >> 4, v = g & 15;
        const float4* s = (const float4*)(emb + (size_t)idx[n] * DIM + v * 8);
        float4 a = s[0], bb = s[1];
        uint4 o;
        o.x = pk2bf(a.x, a.y);  o.y = pk2bf(a.z, a.w);
        o.z = pk2bf(bb.x, bb.y); o.w = pk2bf(bb.z, bb.w);
        *(uint4*)(xb + (size_t)n * DIM + v * 8) = o;
    } else {
        // ---- wtrans-v2 ----
        __shared__ float tile[32][33];
        __shared__ float scomp[20][N_BASES];
        int wb = b - INIT_B - GATH_B;               // 0..63
        int layer = wb >> 5;
        int chunk = (wb >> 4) & 1;                  // rel chunk: 0 -> 0..19, 1 -> 20..39 (+root)
        int tb    = wb & 15;
        const float* comp  = layer ? comp1  : comp0;
        const float* bases = layer ? bases1 : bases0;
        const float* root  = layer ? root1  : root0;
        int k0 = (tb >> 2) * 32, n0 = (tb & 3) * 32;
        int cr0 = chunk * 20;
        int tr = t >> 5, tc = t & 31;
        // stage comp rows for this chunk
        for (int i = t; i < 20 * N_BASES; i += 256)
            scomp[i / N_BASES][i % N_BASES] = comp[(cr0 + i / N_BASES) * N_BASES + i % N_BASES];
        __syncthreads();
        // accumulate 20 relations over all bases
        float acc[20][4];
        #pragma unroll
        for (int r = 0; r < 20; ++r)
            #pragma unroll
            for (int i = 0; i < 4; ++i) acc[r][i] = 0.f;
        for (int bs = 0; bs < N_BASES; ++bs) {
            float t4[4];
            #pragma unroll
            for (int i = 0; i < 4; ++i)
                t4[i] = bases[((size_t)bs * DIM + k0 + tr + 8 * i) * DIM + n0 + tc];
            #pragma unroll
            for (int r = 0; r < 20; ++r) {
                float cv = scomp[r][bs];
                #pragma unroll
                for (int i = 0; i < 4; ++i) acc[r][i] += cv * t4[i];
            }
        }
        // transpose + bf16 store, one relation at a time
        size_t lbase = (size_t)layer * NSLOT * DIM * DIM;
        #pragma unroll 1
        for (int r = 0; r < 20; ++r) {
            __syncthreads();
            #pragma unroll
            for (int i = 0; i < 4; ++i) tile[tr + 8 * i][tc] = acc[r][i];
            __syncthreads();
            size_t obase = lbase + (size_t)(cr0 + r) * DIM * DIM;
            #pragma unroll
            for (int i = 0; i < 4; ++i) {
                int rr = tr + 8 * i;
                Wt[obase + (size_t)(n0 + rr) * DIM + k0 + tc] = f2bf(tile[tc][rr]);
            }
        }
        if (chunk == 1) {   // root -> slot 40
            __syncthreads();
            #pragma unroll
            for (int i = 0; i < 4; ++i)
                tile[tr + 8 * i][tc] = root[(size_t)(k0 + tr + 8 * i) * DIM + n0 + tc];
            __syncthreads();
            size_t obase = lbase + (size_t)R_REL * DIM * DIM;
            #pragma unroll
            for (int i = 0; i < 4; ++i) {
                int rr = tr + 8 * i;
                Wt[obase + (size_t)(n0 + rr) * DIM + k0 + tc] = f2bf(tile[tc][rr]);
            }
        }
    }
}

// ---------------- counts c[dst*R+et], relation hist h, dst degree ----------------
__global__ void count_kernel(const int* __restrict__ ei, const int* __restrict__ et,
                             int* __restrict__ c, int* __restrict__ h,
                             int* __restrict__ deg) {
    __shared__ int hloc[R_REL];
    int t = threadIdx.x;
    if (t < R_REL) hloc[t] = 0;
    __syncthreads();
    int e = blockIdx.x * blockDim.x + t;
    if (e < N_EDGES) {
        int dst = ei[N_EDGES + e];
        int r   = et[e];
        atomicAdd(&c[dst * R_REL + r], 1);
        atomicAdd(&deg[dst], 1);
        atomicAdd(&hloc[r], 1);
    }
    __syncthreads();
    if (t < R_REL && hloc[t]) atomicAdd(&h[t], hloc[t]);
}

// ---------------- scans (one 1024-thread block): dst-CSR ptr, relation off, block->rel LUT ----
__global__ void scans_kernel(const int* __restrict__ deg, const int* __restrict__ h,
                             int* __restrict__ ptr, int* __restrict__ off,
                             int* __restrict__ brel) {
    __shared__ int part[1024];
    __shared__ int soff[R_REL + 2];
    const int CHn = (N_NODES + 1023) / 1024;   // 20
    int t = threadIdx.x;
    int s = 0;
    for (int i = 0; i < CHn; ++i) {
        int idx = t * CHn + i;
        if (idx < N_NODES) s += deg[idx] + 1;  // +1 = root slot
    }
    part[t] = s;
    __syncthreads();
    for (int d = 1; d < 1024; d <<= 1) {
        int v = (t >= d) ? part[t - d] : 0;
        __syncthreads();
        part[t] += v;
        __syncthreads();
    }
    int base = (t > 0) ? part[t - 1] : 0;
    for (int i = 0; i < CHn; ++i) {
        int idx = t * CHn + i;
        if (idx < N_NODES) { ptr[idx] = base; base += deg[idx] + 1; }
    }
    if (t == 0) {
        ptr[N_NODES] = NE2;
        int acc = 0;
        soff[0] = 0; off[0] = 0;
        for (int r = 0; r < R_REL; ++r) {
            acc += ((h[r] + EB - 1) / EB) * EB;
            soff[r + 1] = acc; off[r + 1] = acc;
        }
        soff[R_REL + 1] = acc + ROOT_PAD;
        off[R_REL + 1]  = acc + ROOT_PAD;
    }
    __syncthreads();
    // block -> relation LUT (pads beyond total -> -1)
    for (int i = t; i < NBLK; i += 1024) {
        int e0 = i * EB;
        int r = -1;
        if (e0 < soff[R_REL + 1]) {
            r = 0;
            while (e0 >= soff[r + 1]) ++r;
        }
        brel[i] = r;
    }
}

// ---------------- placement (finv inline) + pad-sentinel fill: real + root + pad slots ----
//   esrc[p] = {src, qpos (dst-CSR position), bits(escale), 0}
__global__ void place_kernel(const int* __restrict__ ei, const int* __restrict__ et,
                             const int* __restrict__ off, int* __restrict__ cur,
                             const int* __restrict__ c_cnt, const int* __restrict__ h,
                             const int* __restrict__ ptr, int* __restrict__ cur2,
                             uint4* __restrict__ esrc) {
    __shared__ int hloc[R_REL];
    __shared__ int base[R_REL];
    int t = threadIdx.x;
    if (t < R_REL) hloc[t] = 0;
    __syncthreads();
    int e = blockIdx.x * blockDim.x + t;       // covers N_EDGES + N_NODES + PADW
    int r = 0, myrank = 0, src = 0, dst = 0;
    bool isEdge = (e < N_EDGES);
    if (isEdge) {
        r = et[e]; src = ei[e]; dst = ei[N_EDGES + e];
        myrank = atomicAdd(&hloc[r], 1);
    }
    __syncthreads();
    if (t < R_REL) base[t] = hloc[t] ? atomicAdd(&cur[t], hloc[t]) : 0;
    __syncthreads();
    if (isEdge) {
        int p = off[r] + base[r] + myrank;
        int q = ptr[dst] + 1 + atomicAdd(&cur2[dst], 1);
        int cnt = c_cnt[dst * R_REL + r];
        float esc = 1.0f / (float)(cnt < 1 ? 1 : cnt);
        esrc[p] = make_uint4((uint)src, (uint)q, __float_as_uint(esc), 0u);
    } else if (e < NE2) {
        int n = e - N_EDGES;
        esrc[off[R_REL] + n] = make_uint4((uint)n, (uint)ptr[n], 0x3f800000u, 0u);
    } else if (e < NE2 + PADW) {
        int i = e - NE2;
        int pr = i >> 7, j = i & (EB - 1);           // pad per slot < EB by construction
        int cnt = (pr < R_REL) ? h[pr] : N_NODES;
        int slot = off[pr] + cnt + j;
        if (slot < off[pr + 1])
            esrc[slot] = make_uint4((uint)-1, (uint)-1, 0u, 0u);
    }
}

// ---------------- MFMA edge GEMM: 512 threads, 8 waves x 16 edges, W in LDS, brel LUT ----
__launch_bounds__(512)
__global__ void edge_mfma_kernel(const uint4* __restrict__ esrc, const int* __restrict__ brel,
                                 const ushort* __restrict__ xb, const ushort* __restrict__ Wt,
                                 ushort* __restrict__ T) {
    __shared__ __align__(16) ushort Ws[DIM * DIM];   // 32 KB, 16B-slot XOR swizzled
    int r = brel[blockIdx.x];                        // uniform scalar
    if (r < 0) return;                               // beyond padded total
    int t = threadIdx.x;
    int e0 = blockIdx.x * EB;
    int wv = t >> 6;            // wave 0..7 -> edges [wv*16, wv*16+16)
    int l  = t & 63;
    int lr = l & 15;            // edge col within subtile / W row within n-tile
    int lk = l >> 4;            // k sub-segment 0..3
    int er = e0 + wv * 16 + lr;
    uint4 es = esrc[er];                             // prefetch: no dependencies

    // cooperative stage of W_r (32 KB) into LDS; 16B slot s of row -> s ^ (row&15)
    const ushort* Wr = Wt + (size_t)r * DIM * DIM;
    #pragma unroll
    for (int i = 0; i < 4; ++i) {
        int idx = t + 512 * i;                       // [0, 2048) 16B slots
        int row = idx >> 4, slot = idx & 15;
        uint4 v = *(const uint4*)(Wr + row * DIM + slot * 8);
        *(uint4*)(&Ws[row * DIM + ((slot ^ (row & 15)) * 8)]) = v;
    }

    // B-fragments (x^T): issue gathers before the barrier so they overlap it
    int s0 = (int)es.x, q0 = (int)es.y;
    float esc = __uint_as_float(es.z);
    const ushort* xp = xb + (size_t)(s0 < 0 ? 0 : s0) * DIM;
    short8 xf[4];
    #pragma unroll
    for (int ks = 0; ks < 4; ++ks)
        xf[ks] = *(const short8*)(xp + (ks * 4 + lk) * 8);
    __syncthreads();

    f32x4 acc[8];
    #pragma unroll
    for (int mt = 0; mt < 8; ++mt) acc[mt] = (f32x4){0.f, 0.f, 0.f, 0.f};

    #pragma unroll
    for (int ks = 0; ks < 4; ++ks) {
        #pragma unroll
        for (int mt = 0; mt < 8; ++mt) {
            int row = mt * 16 + lr;
            int slot = (ks * 4 + lk) ^ lr;           // row&15 == lr
            short8 wf = *(const short8*)(&Ws[row * DIM + slot * 8]);
            acc[mt] = __builtin_amdgcn_mfma_f32_16x16x32_bf16(wf, xf[ks], acc[mt], 0, 0, 0);
        }
    }

    // lane holds D[n = mt*16 + lk*4 + i][edge]; write to dst-CSR row q (skip padding q<0)
    if (q0 >= 0) {
        ushort* T0 = T + (size_t)q0 * DIM;
        #pragma unroll
        for (int mt = 0; mt < 8; ++mt) {
            uint2 p0;
            p0.x = pk2bf(acc[mt][0] * esc, acc[mt][1] * esc);
            p0.y = pk2bf(acc[mt][2] * esc, acc[mt][3] * esc);
            *(uint2*)(T0 + mt * 16 + lk * 4) = p0;
        }
    }
}

// ---------------- aggregate: y[n,:] = bias + sum_{q in [ptr[n],ptr[n+1])} T[q,:] (sequential);
//   2 nodes per 128-thread block.
template<int OUT_BF16>
__global__ void aggregate_kernel(const int* __restrict__ ptr, const ushort* __restrict__ T,
                                 const float* __restrict__ bias, void* __restrict__ yout) {
    int t = threadIdx.x;
    int n = blockIdx.x * 2 + (t >> 6);   // N_NODES is even
    int tt = t & 63;                     // 64 threads per node, 2 cols each
    int s0 = ptr[n], s1 = ptr[n + 1];
    float a0 = bias[2 * tt], a1 = bias[2 * tt + 1];
    for (int q = s0; q < s1; ++q) {
        uint v = *(const uint*)(T + (size_t)q * DIM + 2 * tt);
        a0 += __uint_as_float(v << 16);
        a1 += __uint_as_float(v & 0xFFFF0000u);
    }
    if (OUT_BF16) {
        ((uint*)yout)[n * 64 + tt] = pk2bf(a0, a1);
    } else {
        ((float2*)yout)[n * 64 + tt] = make_float2(a0, a1);
    }
}

extern "C" void kernel_launch(void* const* d_in, const int* in_sizes, int n_in,
                              void* d_out, int out_size, void* d_ws, size_t ws_size,
                              hipStream_t stream) {
    const int*   node_index = (const int*)d_in[0];
    const int*   edge_index = (const int*)d_in[1];
    const int*   edge_type  = (const int*)d_in[2];
    // d_in[3] node_frequency: unused
    const float* node_emb   = (const float*)d_in[4];
    const float* comp0  = (const float*)d_in[5];
    const float* bases0 = (const float*)d_in[6];
    const float* root0  = (const float*)d_in[7];
    const float* bias0  = (const float*)d_in[8];
    const float* comp1  = (const float*)d_in[9];
    const float* bases1 = (const float*)d_in[10];
    const float* root1  = (const float*)d_in[11];
    const float* bias1  = (const float*)d_in[12];
    float* out = (float*)d_out;

    // ---- workspace layout (~109 MB) ----
    char* ws = (char*)d_ws;
    int*    c_cnt  = (int*)   (ws);                 //  3,200,000
    ushort* Wt     = (ushort*)(ws +  3200000);      //  2,686,976 (2 layers x 41 slots bf16 [n][k])
    ushort* x0b    = (ushort*)(ws +  5886976);      //  5,120,000
    ushort* y0b    = (ushort*)(ws + 11006976);      //  5,120,000
    uint4*  esrc   = (uint4*) (ws + 16126976);      //  5,523,456 (P2_MAX * 16B)
    int*    meta   = (int*)   (ws + 21650432);      //  1,024: off[42]@0 h[40]@64 cur[40]@128
    int*    cur2   = (int*)   (ws + 21651456);      //  80,000 (contiguous after meta)
    int*    deg    = (int*)   (ws + 21731456);      //  80,000 (contiguous after cur2)
    int*    ptr    = (int*)   (ws + 21811456);      //  80,256 (20001 ints)
    int*    brel   = (int*)   (ws + 21891712);      //  12,288 (2697 ints)
    ushort* T      = (ushort*)(ws + 21904000);      // 87,040,000 (NE2 * 128 bf16)
    int* off = meta;
    int* h   = meta + 64;
    int* cur = meta + 128;

    // ---- build graph structures (shared by both layers) ----
    prep_kernel<<<INIT_B + GATH_B + WT_B, 256, 0, stream>>>(
        c_cnt, meta, node_emb, node_index, x0b,
        comp0, bases0, root0, comp1, bases1, root1, Wt);
    count_kernel<<<(N_EDGES + 255) / 256, 256, 0, stream>>>(edge_index, edge_type, c_cnt, h, deg);
    scans_kernel<<<1, 1024, 0, stream>>>(deg, h, ptr, off, brel);
    place_kernel<<<(NE2 + PADW + 255) / 256, 256, 0, stream>>>(
        edge_index, edge_type, off, cur, c_cnt, h, ptr, cur2, esrc);

    // ---- layer 0 ----
    edge_mfma_kernel<<<NBLK, 512, 0, stream>>>(esrc, brel, x0b, Wt, T);
    aggregate_kernel<1><<<N_NODES / 2, 128, 0, stream>>>(ptr, T, bias0, y0b);

    // ---- layer 1 ----
    edge_mfma_kernel<<<NBLK, 512, 0, stream>>>(esrc, brel, y0b,
                                               Wt + (size_t)NSLOT * DIM * DIM, T);
    aggregate_kernel<0><<<N_NODES / 2, 128, 0, stream>>>(ptr, T, bias1, out);
}

// Round 15
// 286.245 us; speedup vs baseline: 1.0019x; 1.0019x over previous
//
#include <hip/hip_runtime.h>

#define N_NODES  20000
#define N_EDGES  320000
#define R_REL    40
#define N_BASES  34
#define DIM      128
#define EB       128                         // edges per block (edge GEMM tile M)
#define P_PAD    (N_EDGES + R_REL * EB)      // 325120: worst-case padded relation edges
#define ROOT_PAD ((N_NODES + EB - 1) / EB * EB)  // 20096
#define P2_MAX   (P_PAD + ROOT_PAD)          // 345216 (root edges = slot 40)
#define NE2      (N_EDGES + N_NODES)         // dst-CSR entries incl. root edges
#define NSLOT    (R_REL + 1)                 // 41 weight slots
#define NBLK     (P2_MAX / EB)               // 2697 static edge blocks
#define PADW     (NSLOT * EB)                // 5248 pad-fill threads in place

#define INIT_B   ((N_NODES * R_REL + 255) / 256)   // 3125
#define GATH_B   (N_NODES * 16 / 256)              // 1250
#define WT_B     64                                // 2 layers x 2 rchunks x 4 ktiles x 4 ntiles

typedef unsigned int uint;
typedef unsigned short ushort;
typedef __attribute__((ext_vector_type(8))) short short8;   // 8 bf16 = 4 VGPRs
typedef __attribute__((ext_vector_type(4))) float f32x4;

__device__ __forceinline__ ushort f2bf(float f) {   // RNE fp32 -> bf16
    uint u = __float_as_uint(f);
    return (ushort)((u + 0x7FFFu + ((u >> 16) & 1u)) >> 16);
}
__device__ __forceinline__ uint pk2bf(float a, float b) {
    return (uint)f2bf(a) | ((uint)f2bf(b) << 16);
}

// ---------------- prep: init (zero) + gather-bf16 + wtrans-v2, one dispatch ----------------
// wtrans-v2: block = (layer, rchunk, ktile, ntile); each thread accumulates 20 relations
// per bases element -> bases read once per rchunk (20x less traffic than per-slot loop).
__global__ void prep_kernel(int* __restrict__ c_cnt, int* __restrict__ meta_cur2_deg,
                            const float* __restrict__ emb, const int* __restrict__ idx,
                            ushort* __restrict__ xb,
                            const float* __restrict__ comp0, const float* __restrict__ bases0,
                            const float* __restrict__ root0,
                            const float* __restrict__ comp1, const float* __restrict__ bases1,
                            const float* __restrict__ root1,
                            ushort* __restrict__ Wt) {
    int b = blockIdx.x;
    int t = threadIdx.x;
    if (b < INIT_B) {
        // ---- init ----
        int i = b * 256 + t;
        if (i < N_NODES * R_REL) c_cnt[i] = 0;
        if (i < 256 + 2 * N_NODES) meta_cur2_deg[i] = 0;   // meta[256]+cur2[20000]+deg[20000]
    } else if (b < INIT_B + GATH_B) {
        // ---- gather + bf16 convert ----
        int g = (b - INIT_B) * 256 + t;
        int n = g >> 4, v = g & 15;
        const float4* s = (const float4*)(emb + (size_t)idx[n] * DIM + v * 8);
        float4 a = s[0], bb = s[1];
        uint4 o;
        o.x = pk2bf(a.x, a.y);  o.y = pk2bf(a.z, a.w);
        o.z = pk2bf(bb.x, bb.y); o.w = pk2bf(bb.z, bb.w);
        *(uint4*)(xb + (size_t)n * DIM + v * 8) = o;
    } else {
        // ---- wtrans-v2 ----
        __shared__ float tile[32][33];
        __shared__ float scomp[20][N_BASES];
        int wb = b - INIT_B - GATH_B;               // 0..63
        int layer = wb >> 5;
        int chunk = (wb >> 4) & 1;                  // rel chunk: 0 -> 0..19, 1 -> 20..39 (+root)
        int tb    = wb & 15;
        const float* comp  = layer ? comp1  : comp0;
        const float* bases = layer ? bases1 : bases0;
        const float* root  = layer ? root1  : root0;
        int k0 = (tb >> 2) * 32, n0 = (tb & 3) * 32;
        int cr0 = chunk * 20;
        int tr = t >> 5, tc = t & 31;
        // stage comp rows for this chunk
        for (int i = t; i < 20 * N_BASES; i += 256)
            scomp[i / N_BASES][i % N_BASES] = comp[(cr0 + i / N_BASES) * N_BASES + i % N_BASES];
        __syncthreads();
        // accumulate 20 relations over all bases
        float acc[20][4];
        #pragma unroll
        for (int r = 0; r < 20; ++r)
            #pragma unroll
            for (int i = 0; i < 4; ++i) acc[r][i] = 0.f;
        for (int bs = 0; bs < N_BASES; ++bs) {
            float t4[4];
            #pragma unroll
            for (int i = 0; i < 4; ++i)
                t4[i] = bases[((size_t)bs * DIM + k0 + tr + 8 * i) * DIM + n0 + tc];
            #pragma unroll
            for (int r = 0; r < 20; ++r) {
                float cv = scomp[r][bs];
                #pragma unroll
                for (int i = 0; i < 4; ++i) acc[r][i] += cv * t4[i];
            }
        }
        // transpose + bf16 store, one relation at a time
        size_t lbase = (size_t)layer * NSLOT * DIM * DIM;
        #pragma unroll 1
        for (int r = 0; r < 20; ++r) {
            __syncthreads();
            #pragma unroll
            for (int i = 0; i < 4; ++i) tile[tr + 8 * i][tc] = acc[r][i];
            __syncthreads();
            size_t obase = lbase + (size_t)(cr0 + r) * DIM * DIM;
            #pragma unroll
            for (int i = 0; i < 4; ++i) {
                int rr = tr + 8 * i;
                Wt[obase + (size_t)(n0 + rr) * DIM + k0 + tc] = f2bf(tile[tc][rr]);
            }
        }
        if (chunk == 1) {   // root -> slot 40
            __syncthreads();
            #pragma unroll
            for (int i = 0; i < 4; ++i)
                tile[tr + 8 * i][tc] = root[(size_t)(k0 + tr + 8 * i) * DIM + n0 + tc];
            __syncthreads();
            size_t obase = lbase + (size_t)R_REL * DIM * DIM;
            #pragma unroll
            for (int i = 0; i < 4; ++i) {
                int rr = tr + 8 * i;
                Wt[obase + (size_t)(n0 + rr) * DIM + k0 + tc] = f2bf(tile[tc][rr]);
            }
        }
    }
}

// ---------------- counts c[dst*R+et], relation hist h, dst degree ----------------
__global__ void count_kernel(const int* __restrict__ ei, const int* __restrict__ et,
                             int* __restrict__ c, int* __restrict__ h,
                             int* __restrict__ deg) {
    __shared__ int hloc[R_REL];
    int t = threadIdx.x;
    if (t < R_REL) hloc[t] = 0;
    __syncthreads();
    int e = blockIdx.x * blockDim.x + t;
    if (e < N_EDGES) {
        int dst = ei[N_EDGES + e];
        int r   = et[e];
        atomicAdd(&c[dst * R_REL + r], 1);
        atomicAdd(&deg[dst], 1);
        atomicAdd(&hloc[r], 1);
    }
    __syncthreads();
    if (t < R_REL && hloc[t]) atomicAdd(&h[t], hloc[t]);
}

// ---------------- scans (one 1024-thread block): dst-CSR ptr, relation off, block->rel LUT ----
__global__ void scans_kernel(const int* __restrict__ deg, const int* __restrict__ h,
                             int* __restrict__ ptr, int* __restrict__ off,
                             int* __restrict__ brel) {
    __shared__ int part[1024];
    __shared__ int soff[R_REL + 2];
    const int CHn = (N_NODES + 1023) / 1024;   // 20
    int t = threadIdx.x;
    int s = 0;
    for (int i = 0; i < CHn; ++i) {
        int idx = t * CHn + i;
        if (idx < N_NODES) s += deg[idx] + 1;  // +1 = root slot
    }
    part[t] = s;
    __syncthreads();
    for (int d = 1; d < 1024; d <<= 1) {
        int v = (t >= d) ? part[t - d] : 0;
        __syncthreads();
        part[t] += v;
        __syncthreads();
    }
    int base = (t > 0) ? part[t - 1] : 0;
    for (int i = 0; i < CHn; ++i) {
        int idx = t * CHn + i;
        if (idx < N_NODES) { ptr[idx] = base; base += deg[idx] + 1; }
    }
    if (t == 0) {
        ptr[N_NODES] = NE2;
        int acc = 0;
        soff[0] = 0; off[0] = 0;
        for (int r = 0; r < R_REL; ++r) {
            acc += ((h[r] + EB - 1) / EB) * EB;
            soff[r + 1] = acc; off[r + 1] = acc;
        }
        soff[R_REL + 1] = acc + ROOT_PAD;
        off[R_REL + 1]  = acc + ROOT_PAD;
    }
    __syncthreads();
    // block -> relation LUT (pads beyond total -> -1)
    for (int i = t; i < NBLK; i += 1024) {
        int e0 = i * EB;
        int r = -1;
        if (e0 < soff[R_REL + 1]) {
            r = 0;
            while (e0 >= soff[r + 1]) ++r;
        }
        brel[i] = r;
    }
}

// ---------------- placement (finv inline) + pad-sentinel fill: real + root + pad slots ----
//   esrc[p] = {src, qpos (dst-CSR position), bits(escale), 0}
__global__ void place_kernel(const int* __restrict__ ei, const int* __restrict__ et,
                             const int* __restrict__ off, int* __restrict__ cur,
                             const int* __restrict__ c_cnt, const int* __restrict__ h,
                             const int* __restrict__ ptr, int* __restrict__ cur2,
                             uint4* __restrict__ esrc) {
    __shared__ int hloc[R_REL];
    __shared__ int base[R_REL];
    int t = threadIdx.x;
    if (t < R_REL) hloc[t] = 0;
    __syncthreads();
    int e = blockIdx.x * blockDim.x + t;       // covers N_EDGES + N_NODES + PADW
    int r = 0, myrank = 0, src = 0, dst = 0;
    bool isEdge = (e < N_EDGES);
    if (isEdge) {
        r = et[e]; src = ei[e]; dst = ei[N_EDGES + e];
        myrank = atomicAdd(&hloc[r], 1);
    }
    __syncthreads();
    if (t < R_REL) base[t] = hloc[t] ? atomicAdd(&cur[t], hloc[t]) : 0;
    __syncthreads();
    if (isEdge) {
        int p = off[r] + base[r] + myrank;
        int q = ptr[dst] + 1 + atomicAdd(&cur2[dst], 1);
        int cnt = c_cnt[dst * R_REL + r];
        float esc = 1.0f / (float)(cnt < 1 ? 1 : cnt);
        esrc[p] = make_uint4((uint)src, (uint)q, __float_as_uint(esc), 0u);
    } else if (e < NE2) {
        int n = e - N_EDGES;
        esrc[off[R_REL] + n] = make_uint4((uint)n, (uint)ptr[n], 0x3f800000u, 0u);
    } else if (e < NE2 + PADW) {
        int i = e - NE2;
        int pr = i >> 7, j = i & (EB - 1);           // pad per slot < EB by construction
        int cnt = (pr < R_REL) ? h[pr] : N_NODES;
        int slot = off[pr] + cnt + j;
        if (slot < off[pr + 1])
            esrc[slot] = make_uint4((uint)-1, (uint)-1, 0u, 0u);
    }
}

// ---------------- MFMA edge GEMM: 512 threads, 8 waves x 16 edges, W in LDS, brel LUT ----
__launch_bounds__(512)
__global__ void edge_mfma_kernel(const uint4* __restrict__ esrc, const int* __restrict__ brel,
                                 const ushort* __restrict__ xb, const ushort* __restrict__ Wt,
                                 ushort* __restrict__ T) {
    __shared__ __align__(16) ushort Ws[DIM * DIM];   // 32 KB, 16B-slot XOR swizzled
    int r = brel[blockIdx.x];                        // uniform scalar
    if (r < 0) return;                               // beyond padded total
    int t = threadIdx.x;
    int e0 = blockIdx.x * EB;
    int wv = t >> 6;            // wave 0..7 -> edges [wv*16, wv*16+16)
    int l  = t & 63;
    int lr = l & 15;            // edge col within subtile / W row within n-tile
    int lk = l >> 4;            // k sub-segment 0..3
    int er = e0 + wv * 16 + lr;
    uint4 es = esrc[er];                             // prefetch: no dependencies

    // cooperative stage of W_r (32 KB) into LDS; 16B slot s of row -> s ^ (row&15)
    const ushort* Wr = Wt + (size_t)r * DIM * DIM;
    #pragma unroll
    for (int i = 0; i < 4; ++i) {
        int idx = t + 512 * i;                       // [0, 2048) 16B slots
        int row = idx >> 4, slot = idx & 15;
        uint4 v = *(const uint4*)(Wr + row * DIM + slot * 8);
        *(uint4*)(&Ws[row * DIM + ((slot ^ (row & 15)) * 8)]) = v;
    }

    // B-fragments (x^T): issue gathers before the barrier so they overlap it
    int s0 = (int)es.x, q0 = (int)es.y;
    float esc = __uint_as_float(es.z);
    const ushort* xp = xb + (size_t)(s0 < 0 ? 0 : s0) * DIM;
    short8 xf[4];
    #pragma unroll
    for (int ks = 0; ks < 4; ++ks)
        xf[ks] = *(const short8*)(xp + (ks * 4 + lk) * 8);
    __syncthreads();

    f32x4 acc[8];
    #pragma unroll
    for (int mt = 0; mt < 8; ++mt) acc[mt] = (f32x4){0.f, 0.f, 0.f, 0.f};

    #pragma unroll
    for (int ks = 0; ks < 4; ++ks) {
        #pragma unroll
        for (int mt = 0; mt < 8; ++mt) {
            int row = mt * 16 + lr;
            int slot = (ks * 4 + lk) ^ lr;           // row&15 == lr
            short8 wf = *(const short8*)(&Ws[row * DIM + slot * 8]);
            acc[mt] = __builtin_amdgcn_mfma_f32_16x16x32_bf16(wf, xf[ks], acc[mt], 0, 0, 0);
        }
    }

    // lane holds D[n = mt*16 + lk*4 + i][edge]; write to dst-CSR row q (skip padding q<0)
    if (q0 >= 0) {
        ushort* T0 = T + (size_t)q0 * DIM;
        #pragma unroll
        for (int mt = 0; mt < 8; ++mt) {
            uint2 p0;
            p0.x = pk2bf(acc[mt][0] * esc, acc[mt][1] * esc);
            p0.y = pk2bf(acc[mt][2] * esc, acc[mt][3] * esc);
            *(uint2*)(T0 + mt * 16 + lk * 4) = p0;
        }
    }
}

// ---------------- aggregate: y[n,:] = bias + sum_{q in [ptr[n],ptr[n+1])} T[q,:] (sequential);
//   2 nodes per 128-thread block.
template<int OUT_BF16>
__global__ void aggregate_kernel(const int* __restrict__ ptr, const ushort* __restrict__ T,
                                 const float* __restrict__ bias, void* __restrict__ yout) {
    int t = threadIdx.x;
    int n = blockIdx.x * 2 + (t >> 6);   // N_NODES is even
    int tt = t & 63;                     // 64 threads per node, 2 cols each
    int s0 = ptr[n], s1 = ptr[n + 1];
    float a0 = bias[2 * tt], a1 = bias[2 * tt + 1];
    for (int q = s0; q < s1; ++q) {
        uint v = *(const uint*)(T + (size_t)q * DIM + 2 * tt);
        a0 += __uint_as_float(v << 16);
        a1 += __uint_as_float(v & 0xFFFF0000u);
    }
    if (OUT_BF16) {
        ((uint*)yout)[n * 64 + tt] = pk2bf(a0, a1);
    } else {
        ((float2*)yout)[n * 64 + tt] = make_float2(a0, a1);
    }
}

extern "C" void kernel_launch(void* const* d_in, const int* in_sizes, int n_in,
                              void* d_out, int out_size, void* d_ws, size_t ws_size,
                              hipStream_t stream) {
    const int*   node_index = (const int*)d_in[0];
    const int*   edge_index = (const int*)d_in[1];
    const int*   edge_type  = (const int*)d_in[2];
    // d_in[3] node_frequency: unused
    const float* node_emb   = (const float*)d_in[4];
    const float* comp0  = (const float*)d_in[5];
    const float* bases0 = (const float*)d_in[6];
    const float* root0  = (const float*)d_in[7];
    const float* bias0  = (const float*)d_in[8];
    const float* comp1  = (const float*)d_in[9];
    const float* bases1 = (const float*)d_in[10];
    const float* root1  = (const float*)d_in[11];
    const float* bias1  = (const float*)d_in[12];
    float* out = (float*)d_out;

    // ---- workspace layout (~109 MB) ----
    char* ws = (char*)d_ws;
    int*    c_cnt  = (int*)   (ws);                 //  3,200,000
    ushort* Wt     = (ushort*)(ws +  3200000);      //  2,686,976 (2 layers x 41 slots bf16 [n][k])
    ushort* x0b    = (ushort*)(ws +  5886976);      //  5,120,000
    ushort* y0b    = (ushort*)(ws + 11006976);      //  5,120,000
    uint4*  esrc   = (uint4*) (ws + 16126976);      //  5,523,456 (P2_MAX * 16B)
    int*    meta   = (int*)   (ws + 21650432);      //  1,024: off[42]@0 h[40]@64 cur[40]@128
    int*    cur2   = (int*)   (ws + 21651456);      //  80,000 (contiguous after meta)
    int*    deg    = (int*)   (ws + 21731456);      //  80,000 (contiguous after cur2)
    int*    ptr    = (int*)   (ws + 21811456);      //  80,256 (20001 ints)
    int*    brel   = (int*)   (ws + 21891712);      //  12,288 (2697 ints)
    ushort* T      = (ushort*)(ws + 21904000);      // 87,040,000 (NE2 * 128 bf16)
    int* off = meta;
    int* h   = meta + 64;
    int* cur = meta + 128;

    // ---- build graph structures (shared by both layers) ----
    prep_kernel<<<INIT_B + GATH_B + WT_B, 256, 0, stream>>>(
        c_cnt, meta, node_emb, node_index, x0b,
        comp0, bases0, root0, comp1, bases1, root1, Wt);
    count_kernel<<<(N_EDGES + 255) / 256, 256, 0, stream>>>(edge_index, edge_type, c_cnt, h, deg);
    scans_kernel<<<1, 1024, 0, stream>>>(deg, h, ptr, off, brel);
    place_kernel<<<(NE2 + PADW + 255) / 256, 256, 0, stream>>>(
        edge_index, edge_type, off, cur, c_cnt, h, ptr, cur2, esrc);

    // ---- layer 0 ----
    edge_mfma_kernel<<<NBLK, 512, 0, stream>>>(esrc, brel, x0b, Wt, T);
    aggregate_kernel<1><<<N_NODES / 2, 128, 0, stream>>>(ptr, T, bias0, y0b);

    // ---- layer 1 ----
    edge_mfma_kernel<<<NBLK, 512, 0, stream>>>(esrc, brel, y0b,
                                               Wt + (size_t)NSLOT * DIM * DIM, T);
    aggregate_kernel<0><<<N_NODES / 2, 128, 0, stream>>>(ptr, T, bias1, out);
}

// Round 16
// 241.683 us; speedup vs baseline: 1.1866x; 1.1844x over previous
//
#include <hip/hip_runtime.h>

#define N_NODES  20000
#define N_EDGES  320000
#define R_REL    40
#define N_BASES  34
#define DIM      128
#define EB       128                         // edges per block (edge GEMM tile M)
#define P_PAD    (N_EDGES + R_REL * EB)      // 325120: worst-case padded relation edges
#define ROOT_PAD ((N_NODES + EB - 1) / EB * EB)  // 20096
#define P2_MAX   (P_PAD + ROOT_PAD)          // 345216 (root edges = slot 40)
#define NE2      (N_EDGES + N_NODES)         // dst-CSR entries incl. root edges
#define NSLOT    (R_REL + 1)                 // 41 weight slots
#define NBLK     (P2_MAX / EB)               // 2697 static edge blocks
#define PADW     (NSLOT * EB)                // 5248 pad-fill threads in place

#define INIT_B   ((N_NODES * R_REL + 255) / 256)   // 3125
#define GATH_B   (N_NODES * 16 / 256)              // 1250
#define WT_B     (2 * NSLOT * 16)                  // 1312 (round-13 per-slot form)

typedef unsigned int uint;
typedef unsigned short ushort;
typedef __attribute__((ext_vector_type(8))) short short8;   // 8 bf16 = 4 VGPRs
typedef __attribute__((ext_vector_type(4))) float f32x4;

__device__ __forceinline__ ushort f2bf(float f) {   // RNE fp32 -> bf16
    uint u = __float_as_uint(f);
    return (ushort)((u + 0x7FFFu + ((u >> 16) & 1u)) >> 16);
}
__device__ __forceinline__ uint pk2bf(float a, float b) {
    return (uint)f2bf(a) | ((uint)f2bf(b) << 16);
}

// ---------------- prep: init (zero) + gather-bf16 + wtrans (per-slot), one dispatch ----------------
__global__ void prep_kernel(int* __restrict__ c_cnt, int* __restrict__ meta_cur2_deg,
                            const float* __restrict__ emb, const int* __restrict__ idx,
                            ushort* __restrict__ xb,
                            const float* __restrict__ comp0, const float* __restrict__ bases0,
                            const float* __restrict__ root0,
                            const float* __restrict__ comp1, const float* __restrict__ bases1,
                            const float* __restrict__ root1,
                            ushort* __restrict__ Wt) {
    int b = blockIdx.x;
    int t = threadIdx.x;
    if (b < INIT_B) {
        // ---- init ----
        int i = b * 256 + t;
        if (i < N_NODES * R_REL) c_cnt[i] = 0;
        if (i < 256 + 2 * N_NODES) meta_cur2_deg[i] = 0;   // meta[256]+cur2[20000]+deg[20000]
    } else if (b < INIT_B + GATH_B) {
        // ---- gather + bf16 convert ----
        int g = (b - INIT_B) * 256 + t;
        int n = g >> 4, v = g & 15;
        const float4* s = (const float4*)(emb + (size_t)idx[n] * DIM + v * 8);
        float4 a = s[0], bb = s[1];
        uint4 o;
        o.x = pk2bf(a.x, a.y);  o.y = pk2bf(a.z, a.w);
        o.z = pk2bf(bb.x, bb.y); o.w = pk2bf(bb.z, bb.w);
        *(uint4*)(xb + (size_t)n * DIM + v * 8) = o;
    } else {
        // ---- wtrans: basis-combine + transpose + bf16, both layers (per-slot, 1312 blocks) ----
        __shared__ float tile[32][33];
        __shared__ float scomp[N_BASES];
        int wb = b - INIT_B - GATH_B;               // 0..1311
        int layer = (wb >= NSLOT * 16) ? 1 : 0;
        int bb2 = wb - layer * NSLOT * 16;
        const float* comp  = layer ? comp1  : comp0;
        const float* bases = layer ? bases1 : bases0;
        const float* root  = layer ? root1  : root0;
        int slot = bb2 >> 4;                        // 0..40
        int tb   = bb2 & 15;
        int k0 = (tb >> 2) * 32, n0 = (tb & 3) * 32;
        int tr = t >> 5, tc = t & 31;
        if (slot < R_REL) {
            if (t < N_BASES) scomp[t] = comp[slot * N_BASES + t];
            __syncthreads();
            #pragma unroll
            for (int i = 0; i < 4; ++i) {
                int kk = tr + 8 * i;
                float acc = 0.f;
                #pragma unroll
                for (int bs = 0; bs < N_BASES; ++bs)
                    acc += scomp[bs] * bases[((size_t)bs * DIM + k0 + kk) * DIM + n0 + tc];
                tile[kk][tc] = acc;
            }
        } else {
            #pragma unroll
            for (int i = 0; i < 4; ++i) {
                int kk = tr + 8 * i;
                tile[kk][tc] = root[(size_t)(k0 + kk) * DIM + n0 + tc];
            }
        }
        __syncthreads();
        size_t obase = ((size_t)layer * NSLOT + slot) * DIM * DIM;
        #pragma unroll
        for (int i = 0; i < 4; ++i) {
            int rr = tr + 8 * i;
            Wt[obase + (size_t)(n0 + rr) * DIM + k0 + tc] = f2bf(tile[tc][rr]);
        }
    }
}

// ---------------- counts c[dst*R+et], relation hist h, dst degree ----------------
__global__ void count_kernel(const int* __restrict__ ei, const int* __restrict__ et,
                             int* __restrict__ c, int* __restrict__ h,
                             int* __restrict__ deg) {
    __shared__ int hloc[R_REL];
    int t = threadIdx.x;
    if (t < R_REL) hloc[t] = 0;
    __syncthreads();
    int e = blockIdx.x * blockDim.x + t;
    if (e < N_EDGES) {
        int dst = ei[N_EDGES + e];
        int r   = et[e];
        atomicAdd(&c[dst * R_REL + r], 1);
        atomicAdd(&deg[dst], 1);
        atomicAdd(&hloc[r], 1);
    }
    __syncthreads();
    if (t < R_REL && hloc[t]) atomicAdd(&h[t], hloc[t]);
}

// ---------------- scans (one 1024-thread block): dst-CSR ptr, relation off, block->rel LUT ----
__global__ void scans_kernel(const int* __restrict__ deg, const int* __restrict__ h,
                             int* __restrict__ ptr, int* __restrict__ off,
                             int* __restrict__ brel) {
    __shared__ int part[1024];
    __shared__ int soff[R_REL + 2];
    const int CHn = (N_NODES + 1023) / 1024;   // 20
    int t = threadIdx.x;
    int s = 0;
    for (int i = 0; i < CHn; ++i) {
        int idx = t * CHn + i;
        if (idx < N_NODES) s += deg[idx] + 1;  // +1 = root slot
    }
    part[t] = s;
    __syncthreads();
    for (int d = 1; d < 1024; d <<= 1) {
        int v = (t >= d) ? part[t - d] : 0;
        __syncthreads();
        part[t] += v;
        __syncthreads();
    }
    int base = (t > 0) ? part[t - 1] : 0;
    for (int i = 0; i < CHn; ++i) {
        int idx = t * CHn + i;
        if (idx < N_NODES) { ptr[idx] = base; base += deg[idx] + 1; }
    }
    if (t == 0) {
        ptr[N_NODES] = NE2;
        int acc = 0;
        soff[0] = 0; off[0] = 0;
        for (int r = 0; r < R_REL; ++r) {
            acc += ((h[r] + EB - 1) / EB) * EB;
            soff[r + 1] = acc; off[r + 1] = acc;
        }
        soff[R_REL + 1] = acc + ROOT_PAD;
        off[R_REL + 1]  = acc + ROOT_PAD;
    }
    __syncthreads();
    // block -> relation LUT (pads beyond total -> -1)
    for (int i = t; i < NBLK; i += 1024) {
        int e0 = i * EB;
        int r = -1;
        if (e0 < soff[R_REL + 1]) {
            r = 0;
            while (e0 >= soff[r + 1]) ++r;
        }
        brel[i] = r;
    }
}

// ---------------- placement (finv inline) + pad-sentinel fill: real + root + pad slots ----
//   esrc[p] = {src, qpos (dst-CSR position), bits(escale), 0}
__global__ void place_kernel(const int* __restrict__ ei, const int* __restrict__ et,
                             const int* __restrict__ off, int* __restrict__ cur,
                             const int* __restrict__ c_cnt, const int* __restrict__ h,
                             const int* __restrict__ ptr, int* __restrict__ cur2,
                             uint4* __restrict__ esrc) {
    __shared__ int hloc[R_REL];
    __shared__ int base[R_REL];
    int t = threadIdx.x;
    if (t < R_REL) hloc[t] = 0;
    __syncthreads();
    int e = blockIdx.x * blockDim.x + t;       // covers N_EDGES + N_NODES + PADW
    int r = 0, myrank = 0, src = 0, dst = 0;
    bool isEdge = (e < N_EDGES);
    if (isEdge) {
        r = et[e]; src = ei[e]; dst = ei[N_EDGES + e];
        myrank = atomicAdd(&hloc[r], 1);
    }
    __syncthreads();
    if (t < R_REL) base[t] = hloc[t] ? atomicAdd(&cur[t], hloc[t]) : 0;
    __syncthreads();
    if (isEdge) {
        int p = off[r] + base[r] + myrank;
        int q = ptr[dst] + 1 + atomicAdd(&cur2[dst], 1);
        int cnt = c_cnt[dst * R_REL + r];
        float esc = 1.0f / (float)(cnt < 1 ? 1 : cnt);
        esrc[p] = make_uint4((uint)src, (uint)q, __float_as_uint(esc), 0u);
    } else if (e < NE2) {
        int n = e - N_EDGES;
        esrc[off[R_REL] + n] = make_uint4((uint)n, (uint)ptr[n], 0x3f800000u, 0u);
    } else if (e < NE2 + PADW) {
        int i = e - NE2;
        int pr = i >> 7, j = i & (EB - 1);           // pad per slot < EB by construction
        int cnt = (pr < R_REL) ? h[pr] : N_NODES;
        int slot = off[pr] + cnt + j;
        if (slot < off[pr + 1])
            esrc[slot] = make_uint4((uint)-1, (uint)-1, 0u, 0u);
    }
}

// ---------------- MFMA edge GEMM: 512 threads, 8 waves x 16 edges, W in LDS, brel LUT ----
__launch_bounds__(512)
__global__ void edge_mfma_kernel(const uint4* __restrict__ esrc, const int* __restrict__ brel,
                                 const ushort* __restrict__ xb, const ushort* __restrict__ Wt,
                                 ushort* __restrict__ T) {
    __shared__ __align__(16) ushort Ws[DIM * DIM];   // 32 KB, 16B-slot XOR swizzled
    int r = brel[blockIdx.x];                        // uniform scalar
    if (r < 0) return;                               // beyond padded total
    int t = threadIdx.x;
    int e0 = blockIdx.x * EB;
    int wv = t >> 6;            // wave 0..7 -> edges [wv*16, wv*16+16)
    int l  = t & 63;
    int lr = l & 15;            // edge col within subtile / W row within n-tile
    int lk = l >> 4;            // k sub-segment 0..3
    int er = e0 + wv * 16 + lr;
    uint4 es = esrc[er];                             // prefetch: no dependencies

    // cooperative stage of W_r (32 KB) into LDS; 16B slot s of row -> s ^ (row&15)
    const ushort* Wr = Wt + (size_t)r * DIM * DIM;
    #pragma unroll
    for (int i = 0; i < 4; ++i) {
        int idx = t + 512 * i;                       // [0, 2048) 16B slots
        int row = idx >> 4, slot = idx & 15;
        uint4 v = *(const uint4*)(Wr + row * DIM + slot * 8);
        *(uint4*)(&Ws[row * DIM + ((slot ^ (row & 15)) * 8)]) = v;
    }

    // B-fragments (x^T): issue gathers before the barrier so they overlap it
    int s0 = (int)es.x, q0 = (int)es.y;
    float esc = __uint_as_float(es.z);
    const ushort* xp = xb + (size_t)(s0 < 0 ? 0 : s0) * DIM;
    short8 xf[4];
    #pragma unroll
    for (int ks = 0; ks < 4; ++ks)
        xf[ks] = *(const short8*)(xp + (ks * 4 + lk) * 8);
    __syncthreads();

    f32x4 acc[8];
    #pragma unroll
    for (int mt = 0; mt < 8; ++mt) acc[mt] = (f32x4){0.f, 0.f, 0.f, 0.f};

    #pragma unroll
    for (int ks = 0; ks < 4; ++ks) {
        #pragma unroll
        for (int mt = 0; mt < 8; ++mt) {
            int row = mt * 16 + lr;
            int slot = (ks * 4 + lk) ^ lr;           // row&15 == lr
            short8 wf = *(const short8*)(&Ws[row * DIM + slot * 8]);
            acc[mt] = __builtin_amdgcn_mfma_f32_16x16x32_bf16(wf, xf[ks], acc[mt], 0, 0, 0);
        }
    }

    // lane holds D[n = mt*16 + lk*4 + i][edge]; write to dst-CSR row q (skip padding q<0)
    if (q0 >= 0) {
        ushort* T0 = T + (size_t)q0 * DIM;
        #pragma unroll
        for (int mt = 0; mt < 8; ++mt) {
            uint2 p0;
            p0.x = pk2bf(acc[mt][0] * esc, acc[mt][1] * esc);
            p0.y = pk2bf(acc[mt][2] * esc, acc[mt][3] * esc);
            *(uint2*)(T0 + mt * 16 + lk * 4) = p0;
        }
    }
}

// ---------------- aggregate v2: 16 threads/node, uint4 (8-col) loads; 8 nodes/128-block ----
template<int OUT_BF16>
__global__ void aggregate_kernel(const int* __restrict__ ptr, const ushort* __restrict__ T,
                                 const float* __restrict__ bias, void* __restrict__ yout) {
    int t = threadIdx.x;
    int n = blockIdx.x * 8 + (t >> 4);   // N_NODES % 8 == 0
    int tt = t & 15;                     // 16 threads per node, 8 cols each
    int s0 = ptr[n], s1 = ptr[n + 1];
    float a[8];
    #pragma unroll
    for (int j = 0; j < 8; ++j) a[j] = bias[tt * 8 + j];
    for (int q = s0; q < s1; ++q) {
        uint4 v = *(const uint4*)(T + (size_t)q * DIM + tt * 8);
        a[0] += __uint_as_float(v.x << 16); a[1] += __uint_as_float(v.x & 0xFFFF0000u);
        a[2] += __uint_as_float(v.y << 16); a[3] += __uint_as_float(v.y & 0xFFFF0000u);
        a[4] += __uint_as_float(v.z << 16); a[5] += __uint_as_float(v.z & 0xFFFF0000u);
        a[6] += __uint_as_float(v.w << 16); a[7] += __uint_as_float(v.w & 0xFFFF0000u);
    }
    if (OUT_BF16) {
        uint4 o;
        o.x = pk2bf(a[0], a[1]); o.y = pk2bf(a[2], a[3]);
        o.z = pk2bf(a[4], a[5]); o.w = pk2bf(a[6], a[7]);
        ((uint4*)yout)[n * 16 + tt] = o;
    } else {
        float4 f0 = make_float4(a[0], a[1], a[2], a[3]);
        float4 f1 = make_float4(a[4], a[5], a[6], a[7]);
        ((float4*)yout)[n * 32 + tt * 2]     = f0;
        ((float4*)yout)[n * 32 + tt * 2 + 1] = f1;
    }
}

extern "C" void kernel_launch(void* const* d_in, const int* in_sizes, int n_in,
                              void* d_out, int out_size, void* d_ws, size_t ws_size,
                              hipStream_t stream) {
    const int*   node_index = (const int*)d_in[0];
    const int*   edge_index = (const int*)d_in[1];
    const int*   edge_type  = (const int*)d_in[2];
    // d_in[3] node_frequency: unused
    const float* node_emb   = (const float*)d_in[4];
    const float* comp0  = (const float*)d_in[5];
    const float* bases0 = (const float*)d_in[6];
    const float* root0  = (const float*)d_in[7];
    const float* bias0  = (const float*)d_in[8];
    const float* comp1  = (const float*)d_in[9];
    const float* bases1 = (const float*)d_in[10];
    const float* root1  = (const float*)d_in[11];
    const float* bias1  = (const float*)d_in[12];
    float* out = (float*)d_out;

    // ---- workspace layout (~109 MB) ----
    char* ws = (char*)d_ws;
    int*    c_cnt  = (int*)   (ws);                 //  3,200,000
    ushort* Wt     = (ushort*)(ws +  3200000);      //  2,686,976 (2 layers x 41 slots bf16 [n][k])
    ushort* x0b    = (ushort*)(ws +  5886976);      //  5,120,000
    ushort* y0b    = (ushort*)(ws + 11006976);      //  5,120,000
    uint4*  esrc   = (uint4*) (ws + 16126976);      //  5,523,456 (P2_MAX * 16B)
    int*    meta   = (int*)   (ws + 21650432);      //  1,024: off[42]@0 h[40]@64 cur[40]@128
    int*    cur2   = (int*)   (ws + 21651456);      //  80,000 (contiguous after meta)
    int*    deg    = (int*)   (ws + 21731456);      //  80,000 (contiguous after cur2)
    int*    ptr    = (int*)   (ws + 21811456);      //  80,256 (20001 ints)
    int*    brel   = (int*)   (ws + 21891712);      //  12,288 (2697 ints)
    ushort* T      = (ushort*)(ws + 21904000);      // 87,040,000 (NE2 * 128 bf16)
    int* off = meta;
    int* h   = meta + 64;
    int* cur = meta + 128;

    // ---- build graph structures (shared by both layers) ----
    prep_kernel<<<INIT_B + GATH_B + WT_B, 256, 0, stream>>>(
        c_cnt, meta, node_emb, node_index, x0b,
        comp0, bases0, root0, comp1, bases1, root1, Wt);
    count_kernel<<<(N_EDGES + 255) / 256, 256, 0, stream>>>(edge_index, edge_type, c_cnt, h, deg);
    scans_kernel<<<1, 1024, 0, stream>>>(deg, h, ptr, off, brel);
    place_kernel<<<(NE2 + PADW + 255) / 256, 256, 0, stream>>>(
        edge_index, edge_type, off, cur, c_cnt, h, ptr, cur2, esrc);

    // ---- layer 0 ----
    edge_mfma_kernel<<<NBLK, 512, 0, stream>>>(esrc, brel, x0b, Wt, T);
    aggregate_kernel<1><<<N_NODES / 8, 128, 0, stream>>>(ptr, T, bias0, y0b);

    // ---- layer 1 ----
    edge_mfma_kernel<<<NBLK, 512, 0, stream>>>(esrc, brel, y0b,
                                               Wt + (size_t)NSLOT * DIM * DIM, T);
    aggregate_kernel<0><<<N_NODES / 8, 128, 0, stream>>>(ptr, T, bias1, out);
}